// Round 2
// 243.569 us; speedup vs baseline: 1.0497x; 1.0497x over previous
//
#include <hip/hip_runtime.h>

typedef __attribute__((ext_vector_type(8))) short bf16x8;
typedef __attribute__((ext_vector_type(8))) _Float16 f16x8;
typedef __attribute__((ext_vector_type(2))) __fp16 fp16v2;
typedef __attribute__((ext_vector_type(16))) float f32x16;

#define DDIM 128
#define NADDR 4096
#define VDIM 512
#define NT 32
#define ITERS (NADDR/NT)
#define LOG2E 1.44269504088896340736f

// pack bf16-trunc(lo) into low short, bf16-trunc(hi) into high short
__device__ __forceinline__ unsigned pkhi(float hi, float lo){
  return __builtin_amdgcn_perm(__float_as_uint(hi), __float_as_uint(lo), 0x07060302u);
}

// Block: 128 m-rows x 128 v-cols, 4 waves. Wave: 32 m x (all 32 n) x 128 v.
// S^T = K.Q^T via mfma_32x32x16_f16 -> lane holds P[m=lane&31][16 n-vals in regs].
// P assembled in-register (pkhi + permlane32_swap) -> PV A-frag; no sP LDS.
// Double-buffered sK/sVt, ONE barrier/iter; t+1 prefetch issued AFTER the
// barrier so its vmcnt-drain point is the NEXT barrier (latency hides under
// the full S+PV compute phase).
__global__ __launch_bounds__(256, 2)
void soft_addr_kernel(const float* __restrict__ sel,
                      const float* __restrict__ bank,
                      const float* __restrict__ addr,
                      float* __restrict__ out)
{
  // sK: [n=32][d=128] f16, stride 136 (272B rows: 16B-aligned, odd dword-sigma)
  // sVt:[v=128][n=32] bf16, stride 40 (80B rows: 16B-aligned)
  __shared__ __align__(16) _Float16 sK[2][32][136];
  __shared__ __align__(16) short  sVt[2][128][40];
  __shared__ float sL[128];

  const int tid  = threadIdx.x;
  const int wave = tid >> 6;
  const int lane = tid & 63;
  const int h    = lane >> 5;      // half-wave
  const int c32  = lane & 31;

  const int bid  = blockIdx.x;
  const int vblk = bid & 3;
  const int mblk = bid >> 2;
  const int m0 = mblk * 128, v0 = vblk * 128;
  const int wm = wave * 32;        // wave's m-row base

  // ---- Q fragments as B operand (col m = c32, rows d = 16*ks + 8*h + j), log2e-scaled
  f16x8 aQ[8];
  {
    const float* q = sel + (size_t)(m0 + wm + c32) * DDIM + 8*h;
    #pragma unroll
    for (int ks = 0; ks < 8; ++ks){
      float4 a = *(const float4*)(q + 16*ks);
      float4 b = *(const float4*)(q + 16*ks + 4);
      f16x8 f;
      f[0]=(_Float16)(a.x*LOG2E); f[1]=(_Float16)(a.y*LOG2E);
      f[2]=(_Float16)(a.z*LOG2E); f[3]=(_Float16)(a.w*LOG2E);
      f[4]=(_Float16)(b.x*LOG2E); f[5]=(_Float16)(b.y*LOG2E);
      f[6]=(_Float16)(b.z*LOG2E); f[7]=(_Float16)(b.w*LOG2E);
      aQ[ks] = f;
    }
  }

  f32x16 oAcc[4];
  #pragma unroll
  for (int jv=0;jv<4;++jv)
    #pragma unroll
    for (int r=0;r<16;++r) oAcc[jv][r] = 0.f;
  float lacc = 0.f;

  // staging maps (256 threads)
  const int kr  = tid >> 4;          // K rows kr, kr+16
  const int kc  = (tid & 15) * 8;    // K col base
  const int vv  = tid & 127;         // V column
  const int vnb = (tid >> 7) * 16;   // V n-base {0,16}

  float4 kreg[2][2];
  float  vreg[16];

  // prologue: load tile 0
  {
    const float* ksrc = addr + (size_t)tid * 8;   // K tile is contiguous
    kreg[0][0] = *(const float4*)(ksrc);
    kreg[0][1] = *(const float4*)(ksrc + 4);
    kreg[1][0] = *(const float4*)(ksrc + 2048);
    kreg[1][1] = *(const float4*)(ksrc + 2052);
    const float* vsrc = bank + (size_t)vnb * VDIM + v0 + vv;
    #pragma unroll
    for (int k=0;k<16;++k) vreg[k] = vsrc[(size_t)k * VDIM];
  }

  for (int t = 0; t < ITERS; ++t){
    const int b = t & 1;

    // ---- write staged tile t -> LDS buf b (f32->f16 / f32->bf16 in-register)
    //      (first use of kreg/vreg: the implicit vmcnt wait lands here, a full
    //       compute phase after the loads were issued)
    #pragma unroll
    for (int c=0;c<2;++c){
      union { f16x8 v; fp16v2 hh[4]; } u;
      u.hh[0] = __builtin_amdgcn_cvt_pkrtz(kreg[c][0].x, kreg[c][0].y);
      u.hh[1] = __builtin_amdgcn_cvt_pkrtz(kreg[c][0].z, kreg[c][0].w);
      u.hh[2] = __builtin_amdgcn_cvt_pkrtz(kreg[c][1].x, kreg[c][1].y);
      u.hh[3] = __builtin_amdgcn_cvt_pkrtz(kreg[c][1].z, kreg[c][1].w);
      *(f16x8*)&sK[b][kr + 16*c][kc] = u.v;
    }
    {
      uint4 p0, p1;
      p0.x = pkhi(vreg[1],  vreg[0]);  p0.y = pkhi(vreg[3],  vreg[2]);
      p0.z = pkhi(vreg[5],  vreg[4]);  p0.w = pkhi(vreg[7],  vreg[6]);
      p1.x = pkhi(vreg[9],  vreg[8]);  p1.y = pkhi(vreg[11], vreg[10]);
      p1.z = pkhi(vreg[13], vreg[12]); p1.w = pkhi(vreg[15], vreg[14]);
      *(uint4*)&sVt[b][vv][vnb]     = p0;
      *(uint4*)&sVt[b][vv][vnb + 8] = p1;
    }

    __syncthreads();   // single barrier per iteration

    // ---- issue tile t+1 global loads NOW: their drain point is the NEXT
    //      barrier, so HBM/L2 latency hides under the compute below (T14)
    {
      const int n1 = ((t+1) & (ITERS-1)) * NT;   // wraps harmlessly on last iter
      const float* ksrc = addr + (size_t)n1 * DDIM + tid * 8;
      kreg[0][0] = *(const float4*)(ksrc);
      kreg[0][1] = *(const float4*)(ksrc + 4);
      kreg[1][0] = *(const float4*)(ksrc + 2048);
      kreg[1][1] = *(const float4*)(ksrc + 2052);
      const float* vsrc = bank + (size_t)(n1 + vnb) * VDIM + v0 + vv;
      #pragma unroll
      for (int k=0;k<16;++k) vreg[k] = vsrc[(size_t)k * VDIM];
    }

    // ---- S^T = K . Q^T : 32n x 32m, K-dim = 128; two independent 4-chains
    f32x16 sAcc0, sAcc1;
    #pragma unroll
    for (int r=0;r<16;++r){ sAcc0[r] = 0.f; sAcc1[r] = 0.f; }
    #pragma unroll
    for (int ks=0; ks<4; ++ks){
      f16x8 aK0 = *(const f16x8*)&sK[b][c32][16*(2*ks)   + 8*h];
      f16x8 aK1 = *(const f16x8*)&sK[b][c32][16*(2*ks+1) + 8*h];
      sAcc0 = __builtin_amdgcn_mfma_f32_32x32x16_f16(aK0, aQ[2*ks],   sAcc0, 0,0,0);
      sAcc1 = __builtin_amdgcn_mfma_f32_32x32x16_f16(aK1, aQ[2*ks+1], sAcc1, 0,0,0);
    }

    // ---- P = 2^S, bf16-trunc; per-lane row-partial sums (m = c32, this half's n)
    unsigned dw[2][4];
    #pragma unroll
    for (int j=0;j<2;++j)
      #pragma unroll
      for (int i=0;i<4;++i){
        float pa = __builtin_amdgcn_exp2f(sAcc0[8*j + 2*i]     + sAcc1[8*j + 2*i]);
        float pb = __builtin_amdgcn_exp2f(sAcc0[8*j + 2*i + 1] + sAcc1[8*j + 2*i + 1]);
        lacc += __uint_as_float(__float_as_uint(pa) & 0xffff0000u);
        lacc += __uint_as_float(__float_as_uint(pb) & 0xffff0000u);
        dw[j][i] = pkhi(pb, pa);
      }

    // ---- PV: assemble A-frag in-register via permlane32_swap, 8 bf16 MFMA
    #pragma unroll
    for (int j=0;j<2;++j){
      auto s02 = __builtin_amdgcn_permlane32_swap(dw[j][0], dw[j][2], false, false);
      auto s13 = __builtin_amdgcn_permlane32_swap(dw[j][1], dw[j][3], false, false);
      union { unsigned u[4]; bf16x8 v; } ap;
      ap.u[0] = s02[0]; ap.u[1] = s13[0]; ap.u[2] = s02[1]; ap.u[3] = s13[1];
      #pragma unroll
      for (int jv=0;jv<4;++jv){
        bf16x8 bV = *(const bf16x8*)&sVt[b][32*jv + c32][16*j + 8*h];
        oAcc[jv] = __builtin_amdgcn_mfma_f32_32x32x16_bf16(ap.v, bV, oAcc[jv], 0,0,0);
      }
    }
  }

  // ---- denominators: combine the two half-wave partials, broadcast via LDS
  float tot = lacc + __shfl_xor(lacc, 32);
  if (lane < 32) sL[wm + c32] = tot;
  __syncthreads();

  // ---- epilogue: divide + store (D: col v = c32, row m = (r&3)+8*(r>>2)+4h)
  #pragma unroll
  for (int r=0;r<16;++r){
    const int mrow = (r&3) + 8*(r>>2) + 4*h;
    const float inv = 1.0f / sL[wm + mrow];
    float* op = out + (size_t)(m0 + wm + mrow) * VDIM + v0 + c32;
    #pragma unroll
    for (int jv=0;jv<4;++jv)
      op[32*jv] = oAcc[jv][r] * inv;
  }
}

extern "C" void kernel_launch(void* const* d_in, const int* in_sizes, int n_in,
                              void* d_out, int out_size, void* d_ws, size_t ws_size,
                              hipStream_t stream) {
  const float* sel  = (const float*)d_in[0];   // [8,2048,128]
  const float* bank = (const float*)d_in[1];   // [4096,512]
  const float* addr = (const float*)d_in[2];   // [4096,128]
  float* out = (float*)d_out;                  // [8,2048,512]
  dim3 grid(512), block(256);
  hipLaunchKernelGGL(soft_addr_kernel, grid, block, 0, stream, sel, bank, addr, out);
}